// Round 2
// baseline (529.195 us; speedup 1.0000x reference)
//
#include <hip/hip_runtime.h>

// Conv2d VALID 3x3: x[32][64][112][112] f32, w[128][64][3][3] f32 -> out[32][128][110][110] f32
// Implicit GEMM on bf16 MFMA 16x16x32. Block: 128co x 256px (16oh x 16ow), 4 waves.
// R2: no W LDS staging (A-frags from L2-resident wp), ONE barrier per block, 3 blocks/CU,
//     vectorized float4 x-staging with bank-spread packed ds_write_b32.

typedef short bf16x8 __attribute__((ext_vector_type(8)));
typedef float f32x4 __attribute__((ext_vector_type(4)));

__device__ __forceinline__ unsigned short f2bf(float f) {
    unsigned int u = __builtin_bit_cast(unsigned int, f);
    unsigned int r = u + 0x7fffu + ((u >> 16) & 1u);   // RNE
    return (unsigned short)(r >> 16);
}
__device__ __forceinline__ unsigned int pack2(float lo, float hi) {
    return (unsigned)f2bf(lo) | ((unsigned)f2bf(hi) << 16);
}

// wp[kh*3+kw][co][ci] bf16, 9*128*64 = 73728 elems
__global__ void wperm_kernel(const float* __restrict__ W, unsigned short* __restrict__ wp) {
    int t = blockIdx.x * 256 + threadIdx.x;
    if (t < 73728) {
        int r  = t >> 13;
        int co = (t >> 6) & 127;
        int ci = t & 63;
        wp[t] = f2bf(W[(co * 64 + ci) * 9 + r]);
    }
}

__global__ __launch_bounds__(256, 3) void conv_mfma(const float* __restrict__ x,
                                                    const unsigned short* __restrict__ wp,
                                                    float* __restrict__ out) {
    // pixel stride 72 shorts = 144 B (36 dw == 4 mod 32 banks)
    __shared__ alignas(16) unsigned short xwin[324 * 72];   // 18x18 px * (64ci+8pad) = 46656 B

    const int tid  = threadIdx.x;
    const int lane = tid & 63;
    const int wv   = tid >> 6;
    const int quad = lane >> 4;
    const int l15  = lane & 15;

    const int b    = blockIdx.x / 49;
    const int tile = blockIdx.x % 49;
    const int oh0  = (tile / 7) * 16;
    const int ow0  = (tile % 7) * 16;

    const float* xb = x + b * 802816;                       // 64*12544

    // ---- stage x window: cols 0..15 via float4 pairs (2 adjacent ci planes) ----
    // task decomposition interleaves 8 ci-groups x 8 row-chunks across a wave:
    //   global: 16 aligned 64B transactions / instr; LDS: packed b32 writes hit all 32 banks.
    for (int t = tid; t < 2304; t += 256) {
        const int cgl = t & 7;
        const int hwl = (t >> 3) & 7;
        const int cgh = (t >> 6) & 3;
        const int hwh = t >> 8;                             // 0..8
        const int cg  = cgh * 8 + cgl;                      // ci pair = 2cg, 2cg+1
        const int hw  = hwh * 8 + hwl;                      // 0..71
        const int hh  = hw >> 2;                            // 0..17
        const int wc  = hw & 3;                             // 0..3 -> cols wc*4..+3
        const int h   = min(oh0 + hh, 111);                 // clamped rows feed only discarded oh
        const float* p0 = xb + (2 * cg) * 12544 + h * 112 + ow0 + wc * 4;
        const f32x4 a = *reinterpret_cast<const f32x4*>(p0);
        const f32x4 c = *reinterpret_cast<const f32x4*>(p0 + 12544);
        unsigned int* dst = reinterpret_cast<unsigned int*>(
            &xwin[(hh * 18 + wc * 4) * 72 + 2 * cg]);
        dst[0]   = pack2(a[0], c[0]);                       // pixel stride = 36 dwords
        dst[36]  = pack2(a[1], c[1]);
        dst[72]  = pack2(a[2], c[2]);
        dst[108] = pack2(a[3], c[3]);
    }
    // ---- halo cols 16,17 (scalar, clamped: garbage only feeds discarded ow) ----
    for (int u = tid; u < 576; u += 256) {
        const int cg  = u & 31;
        const int hh  = u >> 5;
        const int h   = min(oh0 + hh, 111);
        const int w16 = min(ow0 + 16, 111);
        const int w17 = min(ow0 + 17, 111);
        const float* p0 = xb + (2 * cg) * 12544 + h * 112;
        unsigned int* dst = reinterpret_cast<unsigned int*>(
            &xwin[(hh * 18 + 16) * 72 + 2 * cg]);
        dst[0]  = pack2(p0[w16], p0[12544 + w16]);
        dst[36] = pack2(p0[w17], p0[12544 + w17]);
    }

    f32x4 acc[8][4];
    const f32x4 zero = {0.0f, 0.0f, 0.0f, 0.0f};
    #pragma unroll
    for (int mt = 0; mt < 8; mt++)
        #pragma unroll
        for (int nt = 0; nt < 4; nt++) acc[mt][nt] = zero;

    __syncthreads();                                        // the ONLY barrier

    for (int r = 0; r < 9; r++) {
        const int kh = r / 3;
        const int kw = r % 3;
        const unsigned short* wplane = wp + r * 8192;       // L2-resident, all blocks share
        #pragma unroll
        for (int cs = 0; cs < 2; cs++) {
            const int ko = cs * 32 + quad * 8;
            bf16x8 bfrag[4];
            #pragma unroll
            for (int nt = 0; nt < 4; nt++)
                bfrag[nt] = *reinterpret_cast<const bf16x8*>(
                    &xwin[((wv * 4 + nt + kh) * 18 + (l15 + kw)) * 72 + ko]);
            #pragma unroll
            for (int mt = 0; mt < 8; mt++) {
                const bf16x8 afrag = *reinterpret_cast<const bf16x8*>(
                    wplane + (mt * 16 + l15) * 64 + ko);    // 16B coalesced from L2
                #pragma unroll
                for (int nt = 0; nt < 4; nt++)
                    acc[mt][nt] = __builtin_amdgcn_mfma_f32_16x16x32_bf16(
                        afrag, bfrag[nt], acc[mt][nt], 0, 0, 0);
            }
        }
    }

    // ---- epilogue: D col(n=ow)=lane&15, row=quad*4+reg ----
    const int owc = ow0 + l15;
    if (owc < 110) {
        float* ob = out + b * 1548800;                      // 128*12100
        #pragma unroll
        for (int mt = 0; mt < 8; mt++) {
            #pragma unroll
            for (int nt = 0; nt < 4; nt++) {
                const int oh = oh0 + wv * 4 + nt;
                if (oh < 110) {
                    #pragma unroll
                    for (int reg = 0; reg < 4; reg++) {
                        const int co = mt * 16 + quad * 4 + reg;
                        ob[(co * 110 + oh) * 110 + owc] = acc[mt][nt][reg];
                    }
                }
            }
        }
    }
}

extern "C" void kernel_launch(void* const* d_in, const int* in_sizes, int n_in,
                              void* d_out, int out_size, void* d_ws, size_t ws_size,
                              hipStream_t stream) {
    const float* x = (const float*)d_in[0];
    const float* W = (const float*)d_in[1];
    float* out = (float*)d_out;
    unsigned short* wp = (unsigned short*)d_ws;             // 147456 B

    wperm_kernel<<<288, 256, 0, stream>>>(W, wp);
    conv_mfma<<<32 * 49, 256, 0, stream>>>(x, wp, out);
}

// Round 3
// 365.927 us; speedup vs baseline: 1.4462x; 1.4462x over previous
//
#include <hip/hip_runtime.h>

// Conv2d VALID 3x3: x[32][64][112][112] f32, w[128][64][3][3] f32 -> out[32][128][110][110] f32
// Implicit GEMM on bf16 MFMA 16x16x32. Block: 128co x 256px (16oh x 16ow), 4 waves.
// R3: W staged per-plane to LDS with REGISTER PREFETCH (barriers never wait on global latency);
//     XCD-aware swizzle: one batch's 49 tiles per XCD -> halo reads / boundary writes hit L2.

typedef short bf16x8 __attribute__((ext_vector_type(8)));
typedef float f32x4 __attribute__((ext_vector_type(4)));

__device__ __forceinline__ unsigned short f2bf(float f) {
    unsigned int u = __builtin_bit_cast(unsigned int, f);
    unsigned int r = u + 0x7fffu + ((u >> 16) & 1u);   // RNE
    return (unsigned short)(r >> 16);
}
__device__ __forceinline__ unsigned int pack2(float lo, float hi) {
    return (unsigned)f2bf(lo) | ((unsigned)f2bf(hi) << 16);
}

// wp[kh*3+kw][co][ci] bf16, 9*128*64 = 73728 elems
__global__ void wperm_kernel(const float* __restrict__ W, unsigned short* __restrict__ wp) {
    int t = blockIdx.x * 256 + threadIdx.x;
    if (t < 73728) {
        int r  = t >> 13;
        int co = (t >> 6) & 127;
        int ci = t & 63;
        wp[t] = f2bf(W[(co * 64 + ci) * 9 + r]);
    }
}

__global__ __launch_bounds__(256, 2) void conv_mfma(const float* __restrict__ x,
                                                    const unsigned short* __restrict__ wp,
                                                    float* __restrict__ out) {
    // pixel/row stride 72 shorts = 144 B (36 dw == 4 mod 32 banks): conflict-free b128 reads
    __shared__ alignas(16) unsigned short xwin[324 * 72];   // 18x18 px * (64ci+8pad) = 46656 B
    __shared__ alignas(16) unsigned short wpl[128 * 72];    // 128co * (64ci+8pad)   = 18432 B

    const int tid  = threadIdx.x;
    const int lane = tid & 63;
    const int wv   = tid >> 6;
    const int quad = lane >> 4;
    const int l15  = lane & 15;

    // XCD swizzle: blocks with idx%8==xcd land on the same XCD; give each XCD whole batches
    // so the 49 tiles of a batch (x = 3.2 MB < 4 MB L2) are co-resident -> halo L2 hits.
    const int blk  = blockIdx.x;            // 1568 = 8 xcd * 196 slots
    const int xcd  = blk & 7;
    const int slot = blk >> 3;              // 0..195
    const int b    = xcd + 8 * (slot / 49);
    const int tile = slot % 49;
    const int oh0  = (tile / 7) * 16;
    const int ow0  = (tile % 7) * 16;

    const float* xb = x + b * 802816;                       // 64*12544

    // ---- prefetch W plane 0 into registers (64 B/thread) ----
    const uint4* wsrc = reinterpret_cast<const uint4*>(wp) + tid * 4;  // plane = 1024 uint4
    uint4 wreg[4];
    #pragma unroll
    for (int j = 0; j < 4; j++) wreg[j] = wsrc[j];

    // ---- stage x window: cols 0..15 via float4 pairs (2 adjacent ci planes) ----
    for (int t = tid; t < 2304; t += 256) {
        const int cgl = t & 7;
        const int hwl = (t >> 3) & 7;
        const int cgh = (t >> 6) & 3;
        const int hwh = t >> 8;                             // 0..8
        const int cg  = cgh * 8 + cgl;                      // ci pair = 2cg, 2cg+1
        const int hw  = hwh * 8 + hwl;                      // 0..71
        const int hh  = hw >> 2;                            // 0..17
        const int wc  = hw & 3;                             // cols wc*4..+3
        const int h   = min(oh0 + hh, 111);                 // clamped rows feed only discarded oh
        const float* p0 = xb + (2 * cg) * 12544 + h * 112 + ow0 + wc * 4;
        const f32x4 a = *reinterpret_cast<const f32x4*>(p0);
        const f32x4 c = *reinterpret_cast<const f32x4*>(p0 + 12544);
        unsigned int* dst = reinterpret_cast<unsigned int*>(
            &xwin[(hh * 18 + wc * 4) * 72 + 2 * cg]);
        dst[0]   = pack2(a[0], c[0]);
        dst[36]  = pack2(a[1], c[1]);
        dst[72]  = pack2(a[2], c[2]);
        dst[108] = pack2(a[3], c[3]);
    }
    // ---- halo cols 16,17 (clamped: garbage only feeds discarded ow) ----
    for (int u = tid; u < 576; u += 256) {
        const int cg  = u & 31;
        const int hh  = u >> 5;
        const int h   = min(oh0 + hh, 111);
        const int w16 = min(ow0 + 16, 111);
        const int w17 = min(ow0 + 17, 111);
        const float* p0 = xb + (2 * cg) * 12544 + h * 112;
        unsigned int* dst = reinterpret_cast<unsigned int*>(
            &xwin[(hh * 18 + 16) * 72 + 2 * cg]);
        dst[0]  = pack2(p0[w16], p0[12544 + w16]);
        dst[36] = pack2(p0[w17], p0[12544 + w17]);
    }

    f32x4 acc[8][4];
    const f32x4 zero = {0.0f, 0.0f, 0.0f, 0.0f};
    #pragma unroll
    for (int mt = 0; mt < 8; mt++)
        #pragma unroll
        for (int nt = 0; nt < 4; nt++) acc[mt][nt] = zero;

    const int co_w   = tid >> 1;                            // wpl write slot
    const int half_w = tid & 1;

    for (int r = 0; r < 9; r++) {
        const int kh = r / 3;
        const int kw = r % 3;

        __syncthreads();   // prior plane's ds_reads already consumed; prefetch vmcnt long done
        {   // registers -> LDS (fast: no global latency on this path)
            uint4* dst = reinterpret_cast<uint4*>(&wpl[co_w * 72 + half_w * 32]);
            #pragma unroll
            for (int j = 0; j < 4; j++) dst[j] = wreg[j];
        }
        if (r < 8) {       // prefetch next plane; latency hidden under this plane's compute
            const uint4* s = wsrc + (r + 1) * 1024;
            #pragma unroll
            for (int j = 0; j < 4; j++) wreg[j] = s[j];
        }
        __syncthreads();   // waits only on the ds_writes above

        #pragma unroll
        for (int cs = 0; cs < 2; cs++) {
            const int ko = cs * 32 + quad * 8;
            bf16x8 bfrag[4];
            #pragma unroll
            for (int nt = 0; nt < 4; nt++)
                bfrag[nt] = *reinterpret_cast<const bf16x8*>(
                    &xwin[((wv * 4 + nt + kh) * 18 + (l15 + kw)) * 72 + ko]);
            #pragma unroll
            for (int mt = 0; mt < 8; mt++) {
                const bf16x8 afrag = *reinterpret_cast<const bf16x8*>(
                    &wpl[(mt * 16 + l15) * 72 + ko]);
                #pragma unroll
                for (int nt = 0; nt < 4; nt++)
                    acc[mt][nt] = __builtin_amdgcn_mfma_f32_16x16x32_bf16(
                        afrag, bfrag[nt], acc[mt][nt], 0, 0, 0);
            }
        }
    }

    // ---- epilogue: D col(n=ow)=lane&15, row=quad*4+reg ----
    const int owc = ow0 + l15;
    if (owc < 110) {
        float* ob = out + b * 1548800;                      // 128*12100
        #pragma unroll
        for (int mt = 0; mt < 8; mt++) {
            #pragma unroll
            for (int nt = 0; nt < 4; nt++) {
                const int oh = oh0 + wv * 4 + nt;
                if (oh < 110) {
                    #pragma unroll
                    for (int reg = 0; reg < 4; reg++) {
                        const int co = mt * 16 + quad * 4 + reg;
                        ob[(co * 110 + oh) * 110 + owc] = acc[mt][nt][reg];
                    }
                }
            }
        }
    }
}

extern "C" void kernel_launch(void* const* d_in, const int* in_sizes, int n_in,
                              void* d_out, int out_size, void* d_ws, size_t ws_size,
                              hipStream_t stream) {
    const float* x = (const float*)d_in[0];
    const float* W = (const float*)d_in[1];
    float* out = (float*)d_out;
    unsigned short* wp = (unsigned short*)d_ws;             // 147456 B

    wperm_kernel<<<288, 256, 0, stream>>>(W, wp);
    conv_mfma<<<32 * 49, 256, 0, stream>>>(x, wp, out);
}